// Round 1
// baseline (187.503 us; speedup 1.0000x reference)
//
#include <hip/hip_runtime.h>
#include <hip/hip_bf16.h>
#include <math.h>

// Problem constants (B,C,H,W,O,K,E) = (8,256,64,64,256,3,3)
// weff[b,o,c,tap] = sum_e gates[b,e]*(experts[e,o,c,tap]+experts[e,o,c+256,tap])
// out[b,o,h,w] = sum_{c,dh,dw} q[b,c,h+dh-1,w+dw-1] * weff[b,o,c,dh*3+dw]
//
// Workspace layout (needs ~27.3 MB):
//   [0)        yctx   : 2048 f32
//   [8192)     logits : 24 f32
//   [16384)    wf     : bf16 [8 b][9 tap][8 ch][256 o][32 cl']   (9,437,184 B)
//   [9453568)  qT     : bf16 [8 b][8 ch][66 hp][66 wp][32 cl']   (17,842,176 B)
// cl' swizzle: group' = (cl>>3) ^ ((x>>1)&3), x = o (for wf) / wp (for qT);
// keeps ds_read_b128 fragment reads at free 2-way bank conflicts.

typedef __bf16 bf16x8 __attribute__((ext_vector_type(8)));
typedef float f32x4 __attribute__((ext_vector_type(4)));

#define AS1 __attribute__((address_space(1)))
#define AS3 __attribute__((address_space(3)))

// ---------------- kernel 1: y_ctx[b,c] = mean_{h,w} y ----------------
__global__ __launch_bounds__(64) void yctx_kernel(const float* __restrict__ y,
                                                  float* __restrict__ yctx) {
  int bc = blockIdx.x;  // b*256 + c
  const float4* p = (const float4*)(y + (size_t)bc * 4096);
  int lane = threadIdx.x;
  float s = 0.f;
  for (int i = lane; i < 1024; i += 64) {
    float4 v = p[i];
    s += v.x + v.y + v.z + v.w;
  }
#pragma unroll
  for (int off = 32; off > 0; off >>= 1) s += __shfl_down(s, off, 64);
  if (lane == 0) yctx[bc] = s * (1.f / 4096.f);
}

// ---------------- kernel 2: logits[b,e] ----------------
__global__ __launch_bounds__(64) void logits_kernel(const float* __restrict__ yctx,
                                                    const float* __restrict__ gw,
                                                    const float* __restrict__ gb,
                                                    float* __restrict__ logits) {
  int be = blockIdx.x;  // b*3 + e
  int b = be / 3, e = be - b * 3;
  int lane = threadIdx.x;
  float s = 0.f;
  for (int c = lane; c < 256; c += 64)
    s += yctx[b * 256 + c] * (gw[c * 3 + e] + gw[(c + 256) * 3 + e]);
#pragma unroll
  for (int off = 32; off > 0; off >>= 1) s += __shfl_down(s, off, 64);
  if (lane == 0) logits[be] = s + gb[e];
}

// ---------------- kernel 3: wf (mixed, folded, bf16, A-ready layout) ----------------
__global__ __launch_bounds__(64) void wbuild_kernel(const float* __restrict__ experts,
                                                    const float* __restrict__ logits,
                                                    __bf16* __restrict__ wf) {
  int bid = blockIdx.x;       // o*8 + ch
  int o = bid >> 3, ch = bid & 7;
  int t = threadIdx.x;
  int cl = t & 31, half = t >> 5;
  // softmax gates for all 8 batches (redundant per-thread; tiny)
  float g[8][3];
#pragma unroll
  for (int b = 0; b < 8; b++) {
    float l0 = logits[b * 3 + 0], l1 = logits[b * 3 + 1], l2 = logits[b * 3 + 2];
    float m = fmaxf(l0, fmaxf(l1, l2));
    float e0 = __expf(l0 - m), e1 = __expf(l1 - m), e2 = __expf(l2 - m);
    float inv = 1.f / (e0 + e1 + e2);
    g[b][0] = e0 * inv; g[b][1] = e1 * inv; g[b][2] = e2 * inv;
  }
  int c = ch * 32 + cl + half * 256;          // i-index into experts (0..511)
  int clp = (((cl >> 3) ^ ((o >> 1) & 3)) << 3) | (cl & 7);  // swizzled store slot
#pragma unroll 1
  for (int tap = 0; tap < 9; tap++) {
    float v[3];
#pragma unroll
    for (int e = 0; e < 3; e++)
      v[e] = experts[(((size_t)e * 256 + o) * 512 + c) * 9 + tap];
    float s[3];
#pragma unroll
    for (int e = 0; e < 3; e++)
      s[e] = v[e] + __shfl_xor(v[e], 32, 64);  // fold c and c+256 halves
    if (half == 0) {
#pragma unroll
      for (int b = 0; b < 8; b++) {
        float val = g[b][0] * s[0] + g[b][1] * s[1] + g[b][2] * s[2];
        wf[((((size_t)b * 9 + tap) * 8 + ch) * 256 + o) * 32 + clp] = (__bf16)val;
      }
    }
  }
}

// ---------------- kernel 4: qT (padded, transposed, bf16, B-ready layout) ----------------
__global__ __launch_bounds__(256) void qt_kernel(const float* __restrict__ q,
                                                 __bf16* __restrict__ qT) {
  int bid = blockIdx.x;          // (b*8 + ch)*66 + hp
  int hp = bid % 66;
  int t2 = bid / 66;
  int ch = t2 & 7;
  int b = t2 >> 3;
  __bf16* dst = qT + (((size_t)(b * 8 + ch) * 66 + hp) * 66) * 32;
  int tid = threadIdx.x;
  if (hp == 0 || hp == 65) {     // top/bottom zero padding rows
    for (int i = tid; i < 66 * 32; i += 256) dst[i] = (__bf16)0.f;
    return;
  }
  __shared__ float tile[32][65];  // +1 pad: conflict-free transpose read
  int h = hp - 1;
  {
    int w = tid & 63, ci = tid >> 6;
#pragma unroll
    for (int j = 0; j < 8; j++) {
      int c = ci * 8 + j;
      tile[c][w] = q[(((size_t)b * 256 + ch * 32 + c) * 64 + h) * 64 + w];
    }
  }
  __syncthreads();
  int cl = tid & 31, wsl = tid >> 5;
  if (tid < 32) dst[tid] = (__bf16)0.f;                      // wp = 0 (w = -1)
  else if (tid < 64) dst[65 * 32 + (tid - 32)] = (__bf16)0.f; // wp = 65 (w = 64)
#pragma unroll
  for (int k = 0; k < 8; k++) {
    int w = wsl * 8 + k;
    int wp = w + 1;
    int clp = (((cl >> 3) ^ ((wp >> 1) & 3)) << 3) | (cl & 7);
    dst[wp * 32 + clp] = (__bf16)tile[cl][w];
  }
}

// ---------------- kernel 5: MFMA conv (9 shifted K=256 GEMMs) ----------------
__global__ __launch_bounds__(256) void conv_kernel(const __bf16* __restrict__ qT,
                                                   const __bf16* __restrict__ wf,
                                                   float* __restrict__ out) {
  __shared__ __align__(16) __bf16 Alds[128 * 32];      // 8 KB: weights [128 o][32 c']
  __shared__ __align__(16) __bf16 Qlds[4 * 66 * 32];   // 16.9 KB: q [4 rows][66 wp][32 c']
  const int tid = threadIdx.x;
  const int lane = tid & 63;
  const int wv = tid >> 6;          // wave 0..3
  const int wm = wv >> 1, wn = wv & 1;  // wave tile: o-half (64), row (h0+wn)
  const int l15 = lane & 15, qd = lane >> 4;

  const int bid = blockIdx.x;       // b*64 + ot*32 + nt
  const int b = bid >> 6;
  const int rem = bid & 63;
  const int o0 = (rem >> 5) * 128;
  const int h0 = (rem & 31) * 2;

  f32x4 acc[4][4];
  {
    f32x4 z = {0.f, 0.f, 0.f, 0.f};
#pragma unroll
    for (int i = 0; i < 4; i++)
#pragma unroll
      for (int j = 0; j < 4; j++) acc[i][j] = z;
  }

  // A-fragment LDS byte offsets (o-row fixed per mi; swizzled group)
  int aoff[4];
#pragma unroll
  for (int mi = 0; mi < 4; mi++) {
    int orow = wm * 64 + mi * 16 + l15;
    int g = (qd ^ ((l15 >> 1) & 3)) << 3;
    aoff[mi] = (orow * 32 + g) * 2;
  }

  const char* qT_b = (const char*)qT + (size_t)b * 8 * 66 * 66 * 32 * 2;

#pragma unroll 1
  for (int ch = 0; ch < 8; ch++) {
    __syncthreads();  // all waves done reading Qlds/Alds of previous chunk
    // stage q rows hp = h0..h0+3 of (b,ch): 16896 B contiguous, global->LDS DMA
    const char* qsrc = qT_b + ((size_t)ch * 66 + h0) * 66 * 32 * 2;
    for (int i = tid; i < 1056; i += 256) {
      int ub = i - lane;  // wave-uniform LDS base chunk
      __builtin_amdgcn_global_load_lds(
          (const AS1 void*)(qsrc + ((size_t)i << 4)),
          (AS3 void*)((char*)Qlds + ((size_t)ub << 4)), 16, 0, 0);
    }
#pragma unroll 1
    for (int tap = 0; tap < 9; tap++) {
      if (tap) __syncthreads();  // done reading Alds of previous tap
      // stage weights [128 o][32 c]: 8192 B contiguous
      const char* asrc = (const char*)wf +
          (((((size_t)b * 9 + tap) * 8 + ch) * 256 + o0) * 32) * 2;
      for (int i = tid; i < 512; i += 256) {
        int ub = i - lane;
        __builtin_amdgcn_global_load_lds(
            (const AS1 void*)(asrc + ((size_t)i << 4)),
            (AS3 void*)((char*)Alds + ((size_t)ub << 4)), 16, 0, 0);
      }
      __syncthreads();  // drains vmcnt: Qlds (first tap) + Alds staged

      const int dh = tap / 3, dw = tap - dh * 3;
      const int r = wn + dh;  // Qlds row 0..3
      bf16x8 af[4];
#pragma unroll
      for (int mi = 0; mi < 4; mi++)
        af[mi] = *(const bf16x8*)((const char*)Alds + aoff[mi]);
#pragma unroll
      for (int ni = 0; ni < 4; ni++) {
        int wp = ni * 16 + l15 + dw;   // 0..65
        int g = (qd ^ ((wp >> 1) & 3)) << 3;
        bf16x8 bfv = *(const bf16x8*)((const char*)Qlds +
                                      ((r * 66 + wp) * 32 + g) * 2);
#pragma unroll
        for (int mi = 0; mi < 4; mi++)
          acc[mi][ni] = __builtin_amdgcn_mfma_f32_16x16x32_bf16(
              af[mi], bfv, acc[mi][ni], 0, 0, 0);
      }
    }
  }

  // epilogue: C/D layout col = lane&15 (w), row = qd*4+rr (o)
  const int hh = h0 + wn;
#pragma unroll
  for (int mi = 0; mi < 4; mi++) {
    int o = o0 + wm * 64 + mi * 16 + qd * 4;
#pragma unroll
    for (int ni = 0; ni < 4; ni++) {
      int w = ni * 16 + l15;
#pragma unroll
      for (int rr = 0; rr < 4; rr++)
        out[(((size_t)b * 256 + (o + rr)) * 64 + hh) * 64 + w] = acc[mi][ni][rr];
    }
  }
}

extern "C" void kernel_launch(void* const* d_in, const int* in_sizes, int n_in,
                              void* d_out, int out_size, void* d_ws, size_t ws_size,
                              hipStream_t stream) {
  (void)in_sizes; (void)n_in; (void)out_size; (void)ws_size;
  const float* q = (const float*)d_in[0];
  const float* y = (const float*)d_in[1];
  const float* experts = (const float*)d_in[2];
  const float* gate_w = (const float*)d_in[3];
  const float* gate_b = (const float*)d_in[4];
  float* out = (float*)d_out;

  char* ws = (char*)d_ws;
  float* yctx = (float*)ws;                         // 8 KB
  float* logits = (float*)(ws + 8192);              // 96 B
  __bf16* wf = (__bf16*)(ws + 16384);               // 9,437,184 B
  __bf16* qT = (__bf16*)(ws + 16384 + 9437184);     // 17,842,176 B

  yctx_kernel<<<2048, 64, 0, stream>>>(y, yctx);
  logits_kernel<<<24, 64, 0, stream>>>(yctx, gate_w, gate_b, logits);
  qt_kernel<<<8 * 8 * 66, 256, 0, stream>>>(q, qT);
  wbuild_kernel<<<2048, 64, 0, stream>>>(experts, logits, wf);
  conv_kernel<<<512, 256, 0, stream>>>(qT, wf, out);
}

// Round 2
// 186.289 us; speedup vs baseline: 1.0065x; 1.0065x over previous
//
#include <hip/hip_runtime.h>
#include <hip/hip_bf16.h>
#include <math.h>

// Problem constants (B,C,H,W,O,K,E) = (8,256,64,64,256,3,3)
// weff[b,o,c,tap] = sum_e gates[b,e]*(experts[e,o,c,tap]+experts[e,o,c+256,tap])
// out[b,o,h,w] = sum_{c,dh,dw} q[b,c,h+dh-1,w+dw-1] * weff[b,o,c,dh*3+dw]
//
// Workspace layout (~27.3 MB):
//   [0)        yctx   : 2048 f32
//   [8192)     logits : 24 f32
//   [16384)    wf     : bf16 [8 b][9 tap][8 ch][256 o][32 cl']   (9,437,184 B)
//   [9453568)  qT     : bf16 [8 b][8 ch][66 hp][66 wp][32 cl']   (17,842,176 B)
// cl' swizzle: group' = (cl>>3) ^ ((x>>1)&3), x = o (for wf) / wp (for qT);
// keeps ds_read_b128 fragment reads at free 2-way bank conflicts.

typedef __bf16 bf16x8 __attribute__((ext_vector_type(8)));
typedef __bf16 bf16x4 __attribute__((ext_vector_type(4)));
typedef float f32x4 __attribute__((ext_vector_type(4)));

#define AS1 __attribute__((address_space(1)))
#define AS3 __attribute__((address_space(3)))

// ---------------- kernel 1: y_ctx[b,c] = mean_{h,w} y ----------------
__global__ __launch_bounds__(64) void yctx_kernel(const float* __restrict__ y,
                                                  float* __restrict__ yctx) {
  int bc = blockIdx.x;  // b*256 + c
  const float4* p = (const float4*)(y + (size_t)bc * 4096);
  int lane = threadIdx.x;
  float s = 0.f;
  for (int i = lane; i < 1024; i += 64) {
    float4 v = p[i];
    s += v.x + v.y + v.z + v.w;
  }
#pragma unroll
  for (int off = 32; off > 0; off >>= 1) s += __shfl_down(s, off, 64);
  if (lane == 0) yctx[bc] = s * (1.f / 4096.f);
}

// ---------------- kernel 2: logits[b,e] ----------------
__global__ __launch_bounds__(64) void logits_kernel(const float* __restrict__ yctx,
                                                    const float* __restrict__ gw,
                                                    const float* __restrict__ gb,
                                                    float* __restrict__ logits) {
  int be = blockIdx.x;  // b*3 + e
  int b = be / 3, e = be - b * 3;
  int lane = threadIdx.x;
  float s = 0.f;
  for (int c = lane; c < 256; c += 64)
    s += yctx[b * 256 + c] * (gw[c * 3 + e] + gw[(c + 256) * 3 + e]);
#pragma unroll
  for (int off = 32; off > 0; off >>= 1) s += __shfl_down(s, off, 64);
  if (lane == 0) logits[be] = s + gb[e];
}

// ---------------- kernel 3: wf (mixed, folded, bf16, A-ready layout) ----------------
// One block per o. Coalesced float4 loads of the contiguous [512c][9tap] slab,
// fold c/c+256 into LDS, then gate-mix and store.
__global__ __launch_bounds__(256) void wbuild_kernel(const float* __restrict__ experts,
                                                     const float* __restrict__ logits,
                                                     __bf16* __restrict__ wf) {
  int o = blockIdx.x;      // 0..255
  int tid = threadIdx.x;
  __shared__ float sf[3][2304];  // folded experts [e][c*9+tap], c<256 (27.6 KB)
  __shared__ float g[8][3];

#pragma unroll
  for (int e = 0; e < 3; e++) {
    const float4* src = (const float4*)(experts + ((size_t)e * 256 + o) * 4608);
    float4* dstp = (float4*)sf[e];
    for (int i = tid; i < 576; i += 256) {
      float4 a = src[i], bq = src[i + 576];  // +576 f4 = +2304 floats = c+256 half
      float4 r;
      r.x = a.x + bq.x; r.y = a.y + bq.y; r.z = a.z + bq.z; r.w = a.w + bq.w;
      dstp[i] = r;
    }
  }
  if (tid < 8) {
    float l0 = logits[tid * 3 + 0], l1 = logits[tid * 3 + 1], l2 = logits[tid * 3 + 2];
    float m = fmaxf(l0, fmaxf(l1, l2));
    float e0 = __expf(l0 - m), e1 = __expf(l1 - m), e2 = __expf(l2 - m);
    float inv = 1.f / (e0 + e1 + e2);
    g[tid][0] = e0 * inv; g[tid][1] = e1 * inv; g[tid][2] = e2 * inv;
  }
  __syncthreads();

  int cl = tid & 31, ch = tid >> 5;   // c = tid
  int clp = (((cl >> 3) ^ ((o >> 1) & 3)) << 3) | (cl & 7);
#pragma unroll 1
  for (int b = 0; b < 8; b++) {
    float g0 = g[b][0], g1 = g[b][1], g2 = g[b][2];
#pragma unroll
    for (int tap = 0; tap < 9; tap++) {
      float v = g0 * sf[0][tid * 9 + tap] + g1 * sf[1][tid * 9 + tap] +
                g2 * sf[2][tid * 9 + tap];
      wf[((((size_t)b * 9 + tap) * 8 + ch) * 256 + o) * 32 + clp] = (__bf16)v;
    }
  }
}

// ---------------- kernel 4: qT (padded, transposed, bf16, B-ready layout) ----------------
__global__ __launch_bounds__(256) void qt_kernel(const float* __restrict__ q,
                                                 __bf16* __restrict__ qT) {
  int bid = blockIdx.x;          // (b*8 + ch)*66 + hp
  int hp = bid % 66;
  int t2 = bid / 66;
  int ch = t2 & 7;
  int b = t2 >> 3;
  __bf16* dst = qT + (((size_t)(b * 8 + ch) * 66 + hp) * 66) * 32;
  int tid = threadIdx.x;
  float4 z4 = {0.f, 0.f, 0.f, 0.f};
  if (hp == 0 || hp == 65) {     // top/bottom zero padding rows: 4224 B
    float4* d4 = (float4*)dst;
    for (int i = tid; i < 264; i += 256) d4[i] = z4;
    return;
  }
  __shared__ float tile2[64][33];  // [w][c]; write banks (w+c)%32 -> free 2-way
  int h = hp - 1;
  {
    int w = tid & 63, ci = tid >> 6;  // ci 0..3
#pragma unroll
    for (int j = 0; j < 8; j++) {
      int c = ci * 8 + j;
      tile2[w][c] = q[(((size_t)b * 256 + ch * 32 + c) * 64 + h) * 64 + w];
    }
  }
  // zero side columns wp=0 / wp=65 (64 B each)
  if (tid < 4) ((float4*)dst)[tid] = z4;
  else if (tid < 8) ((float4*)(dst + 65 * 32))[tid - 4] = z4;
  __syncthreads();

  int a = tid & 7, wsl = tid >> 3;    // a: c-quad, wsl: 0..31 (2 w each)
  int cl4 = a * 4;
#pragma unroll
  for (int k = 0; k < 2; k++) {
    int w = wsl * 2 + k, wp = w + 1;
    int clp4 = (((cl4 >> 3) ^ ((wp >> 1) & 3)) << 3) | (cl4 & 7);
    float v0 = tile2[w][cl4 + 0], v1 = tile2[w][cl4 + 1];
    float v2 = tile2[w][cl4 + 2], v3 = tile2[w][cl4 + 3];
    bf16x4 r = {(__bf16)v0, (__bf16)v1, (__bf16)v2, (__bf16)v3};
    *(bf16x4*)(dst + wp * 32 + clp4) = r;  // 8B store, 8-aligned
  }
}

// ---------------- kernel 5: MFMA conv (9 shifted K=256 GEMMs, pipelined) ----------------
__global__ __launch_bounds__(256) void conv_kernel(const __bf16* __restrict__ qT,
                                                   const __bf16* __restrict__ wf,
                                                   float* __restrict__ out) {
  __shared__ __align__(16) __bf16 Alds[2][128 * 32];     // 2 x 8 KB
  __shared__ __align__(16) __bf16 Qlds[2][4 * 66 * 32];  // 2 x 16.9 KB
  const int tid = threadIdx.x;
  const int lane = tid & 63;
  const int wv = tid >> 6;
  const int wm = wv >> 1, wn = wv & 1;
  const int l15 = lane & 15, qd = lane >> 4;

  const int bid = blockIdx.x;       // b*64 + ot*32 + nt
  const int b = bid >> 6;
  const int rem = bid & 63;
  const int o0 = (rem >> 5) * 128;
  const int h0 = (rem & 31) * 2;

  f32x4 acc[4][4];
  {
    f32x4 z = {0.f, 0.f, 0.f, 0.f};
#pragma unroll
    for (int i = 0; i < 4; i++)
#pragma unroll
      for (int j = 0; j < 4; j++) acc[i][j] = z;
  }

  int aoff[4];
#pragma unroll
  for (int mi = 0; mi < 4; mi++) {
    int orow = wm * 64 + mi * 16 + l15;
    int g = (qd ^ ((l15 >> 1) & 3)) << 3;
    aoff[mi] = (orow * 32 + g) * 2;
  }

  const char* qT_b = (const char*)qT + (size_t)b * 8 * 66 * 66 * 32 * 2;
  const char* wf_b = (const char*)wf + (size_t)b * 9 * 8 * 256 * 32 * 2;

  // ---- prologue: stage Q(ch=0) -> Qlds[0], A(tap=0,ch=0) -> Alds[0]
  {
    const char* qsrc = qT_b + ((size_t)h0) * 66 * 32 * 2;
    for (int i = tid; i < 1056; i += 256) {
      int ub = i - lane;
      __builtin_amdgcn_global_load_lds((const AS1 void*)(qsrc + ((size_t)i << 4)),
                                       (AS3 void*)((char*)Qlds[0] + ((size_t)ub << 4)),
                                       16, 0, 0);
    }
    const char* asrc = wf_b + ((size_t)o0) * 32 * 2;
    for (int i = tid; i < 512; i += 256) {
      int ub = i - lane;
      __builtin_amdgcn_global_load_lds((const AS1 void*)(asrc + ((size_t)i << 4)),
                                       (AS3 void*)((char*)Alds[0] + ((size_t)ub << 4)),
                                       16, 0, 0);
    }
    __syncthreads();
  }

  int s = 0;
#pragma unroll 1
  for (int ch = 0; ch < 8; ch++) {
    int dh = 0, dw = 0;
#pragma unroll 1
    for (int tap = 0; tap < 9; tap++, s++) {
      // prefetch next A tile (one step ahead) into the other buffer
      if (s < 71) {
        int tapn = (tap == 8) ? 0 : tap + 1;
        int chn = (tap == 8) ? ch + 1 : ch;
        const char* asrc = wf_b + (((size_t)(tapn * 8 + chn) * 256 + o0) * 32) * 2;
        char* adst = (char*)Alds[(s + 1) & 1];
        for (int i = tid; i < 512; i += 256) {
          int ub = i - lane;
          __builtin_amdgcn_global_load_lds((const AS1 void*)(asrc + ((size_t)i << 4)),
                                           (AS3 void*)(adst + ((size_t)ub << 4)),
                                           16, 0, 0);
        }
      }
      // prefetch next ch's Q rows mid-way through this ch
      if (tap == 4 && ch < 7) {
        const char* qsrc = qT_b + ((size_t)(ch + 1) * 66 + h0) * 66 * 32 * 2;
        char* qdst = (char*)Qlds[(ch + 1) & 1];
        for (int i = tid; i < 1056; i += 256) {
          int ub = i - lane;
          __builtin_amdgcn_global_load_lds((const AS1 void*)(qsrc + ((size_t)i << 4)),
                                           (AS3 void*)(qdst + ((size_t)ub << 4)),
                                           16, 0, 0);
        }
      }

      // compute (ch, tap) from Alds[s&1], Qlds[ch&1]
      const char* Ab = (const char*)Alds[s & 1];
      const char* Qb = (const char*)Qlds[ch & 1];
      const int r = wn + dh;
      bf16x8 af[4];
#pragma unroll
      for (int mi = 0; mi < 4; mi++)
        af[mi] = *(const bf16x8*)(Ab + aoff[mi]);
#pragma unroll
      for (int ni = 0; ni < 4; ni++) {
        int wp = ni * 16 + l15 + dw;   // 0..65
        int g = (qd ^ ((wp >> 1) & 3)) << 3;
        bf16x8 bfv = *(const bf16x8*)(Qb + ((r * 66 + wp) * 32 + g) * 2);
#pragma unroll
        for (int mi = 0; mi < 4; mi++)
          acc[mi][ni] = __builtin_amdgcn_mfma_f32_16x16x32_bf16(
              af[mi], bfv, acc[mi][ni], 0, 0, 0);
      }
      __syncthreads();  // readers done + prefetch drained
      if (++dw == 3) { dw = 0; ++dh; }
    }
  }

  // epilogue: C/D layout col = lane&15 (w), row = qd*4+rr (o)
  const int hh = h0 + wn;
#pragma unroll
  for (int mi = 0; mi < 4; mi++) {
    int o = o0 + wm * 64 + mi * 16 + qd * 4;
#pragma unroll
    for (int ni = 0; ni < 4; ni++) {
      int w = ni * 16 + l15;
#pragma unroll
      for (int rr = 0; rr < 4; rr++)
        out[(((size_t)b * 256 + (o + rr)) * 64 + hh) * 64 + w] = acc[mi][ni][rr];
    }
  }
}

extern "C" void kernel_launch(void* const* d_in, const int* in_sizes, int n_in,
                              void* d_out, int out_size, void* d_ws, size_t ws_size,
                              hipStream_t stream) {
  (void)in_sizes; (void)n_in; (void)out_size; (void)ws_size;
  const float* q = (const float*)d_in[0];
  const float* y = (const float*)d_in[1];
  const float* experts = (const float*)d_in[2];
  const float* gate_w = (const float*)d_in[3];
  const float* gate_b = (const float*)d_in[4];
  float* out = (float*)d_out;

  char* ws = (char*)d_ws;
  float* yctx = (float*)ws;                         // 8 KB
  float* logits = (float*)(ws + 8192);              // 96 B
  __bf16* wf = (__bf16*)(ws + 16384);               // 9,437,184 B
  __bf16* qT = (__bf16*)(ws + 16384 + 9437184);     // 17,842,176 B

  yctx_kernel<<<2048, 64, 0, stream>>>(y, yctx);
  logits_kernel<<<24, 64, 0, stream>>>(yctx, gate_w, gate_b, logits);
  qt_kernel<<<8 * 8 * 66, 256, 0, stream>>>(q, qT);
  wbuild_kernel<<<256, 256, 0, stream>>>(experts, logits, wf);
  conv_kernel<<<512, 256, 0, stream>>>(qT, wf, out);
}

// Round 3
// 178.295 us; speedup vs baseline: 1.0516x; 1.0448x over previous
//
#include <hip/hip_runtime.h>
#include <hip/hip_bf16.h>
#include <math.h>

// Problem constants (B,C,H,W,O,K,E) = (8,256,64,64,256,3,3)
// weff[b,o,c,tap] = sum_e gates[b,e]*(experts[e,o,c,tap]+experts[e,o,c+256,tap])
// out[b,o,h,w] = sum_{c,dh,dw} q[b,c,h+dh-1,w+dw-1] * weff[b,o,c,dh*3+dw]
//
// Workspace layout (~27.3 MB):
//   [0)        yctx   : 2048 f32
//   [8192)     logits : 24 f32
//   [16384)    wf     : bf16 [8 b][9 tap][8 ch][256 o][32 c]     (9,437,184 B)  UNSWIZZLED
//   [9453568)  qT     : bf16 [8 b][8 ch][66 hp][66 wp][32 cl']   (17,842,176 B)
// qT cl' swizzle: group' = (cl>>3) ^ ((wp>>1)&3); keeps ds_read_b128 B-fragment
// reads at free 2-way bank conflicts. wf is read global->VGPR (no LDS), so no swizzle.

typedef __bf16 bf16x8 __attribute__((ext_vector_type(8)));
typedef __bf16 bf16x4 __attribute__((ext_vector_type(4)));
typedef float f32x4 __attribute__((ext_vector_type(4)));

#define AS1 __attribute__((address_space(1)))
#define AS3 __attribute__((address_space(3)))

// ---------------- kernel 1: y_ctx[b,c] = mean_{h,w} y ----------------
__global__ __launch_bounds__(64) void yctx_kernel(const float* __restrict__ y,
                                                  float* __restrict__ yctx) {
  int bc = blockIdx.x;  // b*256 + c
  const float4* p = (const float4*)(y + (size_t)bc * 4096);
  int lane = threadIdx.x;
  float s = 0.f;
  for (int i = lane; i < 1024; i += 64) {
    float4 v = p[i];
    s += v.x + v.y + v.z + v.w;
  }
#pragma unroll
  for (int off = 32; off > 0; off >>= 1) s += __shfl_down(s, off, 64);
  if (lane == 0) yctx[bc] = s * (1.f / 4096.f);
}

// ---------------- kernel 2: logits[b,e] ----------------
__global__ __launch_bounds__(64) void logits_kernel(const float* __restrict__ yctx,
                                                    const float* __restrict__ gw,
                                                    const float* __restrict__ gb,
                                                    float* __restrict__ logits) {
  int be = blockIdx.x;  // b*3 + e
  int b = be / 3, e = be - b * 3;
  int lane = threadIdx.x;
  float s = 0.f;
  for (int c = lane; c < 256; c += 64)
    s += yctx[b * 256 + c] * (gw[c * 3 + e] + gw[(c + 256) * 3 + e]);
#pragma unroll
  for (int off = 32; off > 0; off >>= 1) s += __shfl_down(s, off, 64);
  if (lane == 0) logits[be] = s + gb[e];
}

// ---------------- kernel 3: wf (mixed, folded, bf16, A-ready layout) ----------------
// One block per o. Coalesced float4 loads of the contiguous [512c][9tap] slab,
// fold c/c+256 into LDS, then gate-mix and store (unswizzled).
__global__ __launch_bounds__(256) void wbuild_kernel(const float* __restrict__ experts,
                                                     const float* __restrict__ logits,
                                                     __bf16* __restrict__ wf) {
  int o = blockIdx.x;      // 0..255
  int tid = threadIdx.x;
  __shared__ float sf[3][2304];  // folded experts [e][c*9+tap], c<256 (27.6 KB)
  __shared__ float g[8][3];

#pragma unroll
  for (int e = 0; e < 3; e++) {
    const float4* src = (const float4*)(experts + ((size_t)e * 256 + o) * 4608);
    float4* dstp = (float4*)sf[e];
    for (int i = tid; i < 576; i += 256) {
      float4 a = src[i], bq = src[i + 576];  // +576 f4 = +2304 floats = c+256 half
      float4 r;
      r.x = a.x + bq.x; r.y = a.y + bq.y; r.z = a.z + bq.z; r.w = a.w + bq.w;
      dstp[i] = r;
    }
  }
  if (tid < 8) {
    float l0 = logits[tid * 3 + 0], l1 = logits[tid * 3 + 1], l2 = logits[tid * 3 + 2];
    float m = fmaxf(l0, fmaxf(l1, l2));
    float e0 = __expf(l0 - m), e1 = __expf(l1 - m), e2 = __expf(l2 - m);
    float inv = 1.f / (e0 + e1 + e2);
    g[tid][0] = e0 * inv; g[tid][1] = e1 * inv; g[tid][2] = e2 * inv;
  }
  __syncthreads();

  int cl = tid & 31, ch = tid >> 5;   // c = tid
#pragma unroll 1
  for (int b = 0; b < 8; b++) {
    float g0 = g[b][0], g1 = g[b][1], g2 = g[b][2];
#pragma unroll
    for (int tap = 0; tap < 9; tap++) {
      float v = g0 * sf[0][tid * 9 + tap] + g1 * sf[1][tid * 9 + tap] +
                g2 * sf[2][tid * 9 + tap];
      wf[((((size_t)b * 9 + tap) * 8 + ch) * 256 + o) * 32 + cl] = (__bf16)v;
    }
  }
}

// ---------------- kernel 4: qT (padded, transposed, bf16, B-ready layout) ----------------
__global__ __launch_bounds__(256) void qt_kernel(const float* __restrict__ q,
                                                 __bf16* __restrict__ qT) {
  int bid = blockIdx.x;          // (b*8 + ch)*66 + hp
  int hp = bid % 66;
  int t2 = bid / 66;
  int ch = t2 & 7;
  int b = t2 >> 3;
  __bf16* dst = qT + (((size_t)(b * 8 + ch) * 66 + hp) * 66) * 32;
  int tid = threadIdx.x;
  float4 z4 = {0.f, 0.f, 0.f, 0.f};
  if (hp == 0 || hp == 65) {     // top/bottom zero padding rows: 4224 B
    float4* d4 = (float4*)dst;
    for (int i = tid; i < 264; i += 256) d4[i] = z4;
    return;
  }
  __shared__ float tile2[64][33];  // [w][c]; write banks (w+c)%32 -> free 2-way
  int h = hp - 1;
  {
    int w = tid & 63, ci = tid >> 6;  // ci 0..3
#pragma unroll
    for (int j = 0; j < 8; j++) {
      int c = ci * 8 + j;
      tile2[w][c] = q[(((size_t)b * 256 + ch * 32 + c) * 64 + h) * 64 + w];
    }
  }
  // zero side columns wp=0 / wp=65 (64 B each)
  if (tid < 4) ((float4*)dst)[tid] = z4;
  else if (tid < 8) ((float4*)(dst + 65 * 32))[tid - 4] = z4;
  __syncthreads();

  int a = tid & 7, wsl = tid >> 3;    // a: c-quad, wsl: 0..31 (2 w each)
  int cl4 = a * 4;
#pragma unroll
  for (int k = 0; k < 2; k++) {
    int w = wsl * 2 + k, wp = w + 1;
    int clp4 = (((cl4 >> 3) ^ ((wp >> 1) & 3)) << 3) | (cl4 & 7);
    float v0 = tile2[w][cl4 + 0], v1 = tile2[w][cl4 + 1];
    float v2 = tile2[w][cl4 + 2], v3 = tile2[w][cl4 + 3];
    bf16x4 r = {(__bf16)v0, (__bf16)v1, (__bf16)v2, (__bf16)v3};
    *(bf16x4*)(dst + wp * 32 + clp4) = r;  // 8B store, 8-aligned
  }
}

// ---------------- kernel 5: MFMA conv — 1 barrier per ch, A in registers ----------------
__global__ __launch_bounds__(256) void conv_kernel(const __bf16* __restrict__ qT,
                                                   const __bf16* __restrict__ wf,
                                                   float* __restrict__ out) {
  __shared__ __align__(16) __bf16 Qlds[2][4 * 66 * 32];  // 2 x 16.9 KB
  const int tid = threadIdx.x;
  const int lane = tid & 63;
  const int wv = tid >> 6;
  const int wm = wv >> 1, wn = wv & 1;
  const int l15 = lane & 15, qd = lane >> 4;

  const int bid = blockIdx.x;
  const int b = bid & 7;            // XCD swizzle: same b -> same XCD (bid%8 heuristic)
  const int rem = bid >> 3;         // 0..63
  const int o0 = (rem >> 5) * 128;
  const int h0 = (rem & 31) * 2;

  f32x4 acc[4][4];
  {
    f32x4 z = {0.f, 0.f, 0.f, 0.f};
#pragma unroll
    for (int i = 0; i < 4; i++)
#pragma unroll
      for (int j = 0; j < 4; j++) acc[i][j] = z;
  }

  const char* qT_b = (const char*)qT + (size_t)b * 8 * 66 * 66 * 32 * 2;
  // A-fragment base: lane reads 16 B at ((o0+wm*64+mi*16+l15)*32 + qd*8)*2
  const char* abase = (const char*)wf + ((size_t)b * 9 * 8 * 256 +
                                         (size_t)(o0 + wm * 64 + l15)) * 64 +
                      (size_t)qd * 16;
  // step (tap,ch) -> byte offset (tap*8+ch)*256*64
  bf16x8 acur[4], anxt[4];

  // ---- prologue: stage Q(ch=0) -> Qlds[0]; load A(tap0,ch0) into regs
  {
    const char* qsrc = qT_b + ((size_t)h0) * 66 * 32 * 2;
    for (int i = tid; i < 1056; i += 256) {
      int ub = i - lane;
      __builtin_amdgcn_global_load_lds((const AS1 void*)(qsrc + ((size_t)i << 4)),
                                       (AS3 void*)((char*)Qlds[0] + ((size_t)ub << 4)),
                                       16, 0, 0);
    }
#pragma unroll
    for (int mi = 0; mi < 4; mi++)
      acur[mi] = *(const bf16x8*)(abase + mi * 1024);
    __syncthreads();  // drain Q0 staging
  }

#pragma unroll 1
  for (int ch = 0; ch < 8; ch++) {
    // prefetch next ch's Q rows into the other buffer — overlaps all 9 taps
    if (ch < 7) {
      const char* qsrc = qT_b + ((size_t)(ch + 1) * 66 + h0) * 66 * 32 * 2;
      char* qdst = (char*)Qlds[(ch + 1) & 1];
      for (int i = tid; i < 1056; i += 256) {
        int ub = i - lane;
        __builtin_amdgcn_global_load_lds((const AS1 void*)(qsrc + ((size_t)i << 4)),
                                         (AS3 void*)(qdst + ((size_t)ub << 4)),
                                         16, 0, 0);
      }
    }
    const char* Qb = (const char*)Qlds[ch & 1];
#pragma unroll
    for (int tap = 0; tap < 9; tap++) {
      // prefetch A for next step (register double-buffer; plain global->VGPR,
      // waited via vmcnt(N) at first use, NOT at any barrier)
      {
        int tapn = (tap == 8) ? 0 : tap + 1;
        int chn = (tap == 8) ? ch + 1 : ch;   // chn==8 on final step: reads into
                                              // qT region (in-bounds), never used
        size_t aoff = ((size_t)(tapn * 8 + chn)) << 14;
#pragma unroll
        for (int mi = 0; mi < 4; mi++)
          anxt[mi] = *(const bf16x8*)(abase + aoff + mi * 1024);
      }
      const int dh = tap / 3, dw = tap - dh * 3;
      const int r = wn + dh;
#pragma unroll
      for (int ni = 0; ni < 4; ni++) {
        int wp = ni * 16 + l15 + dw;   // 0..65
        int g = (qd ^ ((wp >> 1) & 3)) << 3;
        bf16x8 bfv = *(const bf16x8*)(Qb + ((r * 66 + wp) * 32 + g) * 2);
#pragma unroll
        for (int mi = 0; mi < 4; mi++)
          acc[mi][ni] = __builtin_amdgcn_mfma_f32_16x16x32_bf16(
              acur[mi], bfv, acc[mi][ni], 0, 0, 0);
      }
#pragma unroll
      for (int mi = 0; mi < 4; mi++) acur[mi] = anxt[mi];
    }
    __syncthreads();  // end of ch: Q(ch+1) staged+drained; buffer reuse safe
  }

  // epilogue: C/D layout col = lane&15 (w), row = qd*4+rr (o)
  const int hh = h0 + wn;
#pragma unroll
  for (int mi = 0; mi < 4; mi++) {
    int o = o0 + wm * 64 + mi * 16 + qd * 4;
#pragma unroll
    for (int ni = 0; ni < 4; ni++) {
      int w = ni * 16 + l15;
#pragma unroll
      for (int rr = 0; rr < 4; rr++)
        out[(((size_t)b * 256 + (o + rr)) * 64 + hh) * 64 + w] = acc[mi][ni][rr];
    }
  }
}

extern "C" void kernel_launch(void* const* d_in, const int* in_sizes, int n_in,
                              void* d_out, int out_size, void* d_ws, size_t ws_size,
                              hipStream_t stream) {
  (void)in_sizes; (void)n_in; (void)out_size; (void)ws_size;
  const float* q = (const float*)d_in[0];
  const float* y = (const float*)d_in[1];
  const float* experts = (const float*)d_in[2];
  const float* gate_w = (const float*)d_in[3];
  const float* gate_b = (const float*)d_in[4];
  float* out = (float*)d_out;

  char* ws = (char*)d_ws;
  float* yctx = (float*)ws;                         // 8 KB
  float* logits = (float*)(ws + 8192);              // 96 B
  __bf16* wf = (__bf16*)(ws + 16384);               // 9,437,184 B
  __bf16* qT = (__bf16*)(ws + 16384 + 9437184);     // 17,842,176 B

  yctx_kernel<<<2048, 64, 0, stream>>>(y, yctx);
  logits_kernel<<<24, 64, 0, stream>>>(yctx, gate_w, gate_b, logits);
  qt_kernel<<<8 * 8 * 66, 256, 0, stream>>>(q, qT);
  wbuild_kernel<<<256, 256, 0, stream>>>(experts, logits, wf);
  conv_kernel<<<512, 256, 0, stream>>>(qT, wf, out);
}